// Round 6
// baseline (103.747 us; speedup 1.0000x reference)
//
#include <hip/hip_runtime.h>
#include <hip/hip_bf16.h>

typedef __attribute__((ext_vector_type(8))) __bf16 bf16x8;
typedef __attribute__((ext_vector_type(4))) float f32x4;
typedef unsigned short u16;

#define NB 8192
#define ND 128
#define NCHUNK 16
#define NEGINF (-__builtin_inff())
#define POSINF (__builtin_inff())

__device__ inline u16 f2b(float f){
  __hip_bfloat16 h = __float2bfloat16(f);
  return *reinterpret_cast<u16*>(&h);
}

// ---- prep: fp32 -> bf16, colp[row] = (sq, p=1/(1-sq), sq*p, lab_bits) ------
// also zeroes the final-reduction cells so fin_k's atomic finish is
// graph-replay-safe (stream order: prep -> gram -> fin every iteration).
extern "C" __global__ __launch_bounds__(256)
void prep_k(const float* __restrict__ x, const int* __restrict__ lab,
            u16* __restrict__ xb, float4* __restrict__ colp,
            float* __restrict__ gred, unsigned int* __restrict__ done)
{
  if (blockIdx.x == 0 && threadIdx.x == 0){
    gred[0] = 0.0f; gred[1] = 0.0f; *done = 0u;
  }
  const int tid = blockIdx.x * 256 + threadIdx.x;
  const int row = tid >> 5;           // 32 threads per row
  const int sub = tid & 31;
  const float4 v = reinterpret_cast<const float4*>(x)[row * 32 + sub];
  float s = v.x*v.x + v.y*v.y + v.z*v.z + v.w*v.w;
  #pragma unroll
  for (int m = 1; m < 32; m <<= 1) s += __shfl_xor(s, m, 32);
  ushort4 o;
  o.x = f2b(v.x); o.y = f2b(v.y); o.z = f2b(v.z); o.w = f2b(v.w);
  reinterpret_cast<ushort4*>(xb)[row * 32 + sub] = o;
  if (sub == 0){
    const float p = 1.0f / (1.0f - s);
    colp[row] = make_float4(s, p, s * p, __int_as_float(lab[row]));
  }
}

// ---- main: bf16 MFMA gram tiles + streaming row max/min --------------------
// grid (64, 16): x = 128-row tile, y = 512-col chunk. 4 waves, each 32 rows.
// K-loop: 8 half-tiles of 64 cols, double-buffered in 2x16KB LDS; stage for
// half-tile s+1 issued before compute(s) (T3-minimum 2-phase).
// PRESSURE DISCIPLINE (rounds 1-2): (256,4) capped regs at 128 -> 20-90 MB
// scratch. (256,3) + rolled pipeline loop: 84 VGPR, no spill.
// ROUND-5 LESSON: colp panel in LDS = bank conflicts (786K) + slower; the
// epilogue colp global loads are L2-hits off the critical path. Reverted.
// ROUND-6: incremental addressing. Stage global srcs and the epilogue colp
// pointer are precomputed per-thread ONCE and advanced by constant strides
// (+16384B / +64 entries per phase) instead of remultiplied every phase
// (~100+ VALU/phase of addr chains that also sat in front of the loads).
extern "C" __global__ __launch_bounds__(256, 3)
void gram_k(const u16* __restrict__ xb, const float4* __restrict__ colp,
            float* __restrict__ ppos, float* __restrict__ pneg)
{
  __shared__ u16 Bt[2][64 * 128];   // 2 x 16 KB double buffer, 256B/col,
                                    // 16B chunks XOR-swizzled by col&15
  const int wid  = threadIdx.x >> 6;
  const int lane = threadIdx.x & 63;
  const int m16  = lane & 15;
  const int quad = lane >> 4;
  const int R0  = blockIdx.x * 128;
  const int C0  = blockIdx.y * 512;
  const int WR0 = R0 + wid * 32;

  // A fragments in registers: A[m=lane&15][k=quad*8+j]
  bf16x8 afrag[2][4];
  #pragma unroll
  for (int mt = 0; mt < 2; ++mt){
    const u16* arow = xb + (WR0 + mt*16 + m16) * ND;
    #pragma unroll
    for (int ks = 0; ks < 4; ++ks)
      afrag[mt][ks] = *reinterpret_cast<const bf16x8*>(arow + ks*32 + quad*8);
  }

  // per-row (C/D row = quad*4 + r) params
  float sqi[8]; int labi[8];
  #pragma unroll
  for (int mt = 0; mt < 2; ++mt)
    #pragma unroll
    for (int r = 0; r < 4; ++r){
      const float4 cp = colp[WR0 + mt*16 + quad*4 + r];
      sqi[mt*4+r]  = cp.x;
      labi[mt*4+r] = __float_as_int(cp.w);
    }

  float vpos[8], vneg[8];
  #pragma unroll
  for (int i = 0; i < 8; ++i){ vpos[i] = NEGINF; vneg[i] = POSINF; }

  // Per-thread staging base pointers, computed ONCE. For chunk c (0..3):
  // brow(c) = wid*16 + c*4 + quad; src(c) = m16 ^ ((c*4+quad)&15)
  // (wid*16 drops out of the &15). addr(s,c) = base_c + s*64*ND.
  // Advanced by +64*ND after each stage call (stage order s = 0..7).
  const u16* sp0 = xb + (C0 + wid*16 + 0*4 + quad) * ND + (m16 ^ ((0*4 + quad) & 15)) * 8;
  const u16* sp1 = xb + (C0 + wid*16 + 1*4 + quad) * ND + (m16 ^ ((1*4 + quad) & 15)) * 8;
  const u16* sp2 = xb + (C0 + wid*16 + 2*4 + quad) * ND + (m16 ^ ((2*4 + quad) & 15)) * 8;
  const u16* sp3 = xb + (C0 + wid*16 + 3*4 + quad) * ND + (m16 ^ ((3*4 + quad) & 15)) * 8;
  // epilogue column-param pointer: advanced by +64 per compute (s = 0..7)
  const float4* cpp = colp + C0 + m16;

  // stage 64 B-rows (16 KB) into buffer b; then advance the base pointers.
  // LDS[col][slot] holds global chunk (slot ^ (col&15)); dest lane-linear.
  auto stage = [&](int b){
    __builtin_amdgcn_global_load_lds(
        (__attribute__((address_space(1))) void*)sp0,
        (__attribute__((address_space(3))) void*)(&Bt[b][(wid*4 + 0) * 512]), 16, 0, 0);
    __builtin_amdgcn_global_load_lds(
        (__attribute__((address_space(1))) void*)sp1,
        (__attribute__((address_space(3))) void*)(&Bt[b][(wid*4 + 1) * 512]), 16, 0, 0);
    __builtin_amdgcn_global_load_lds(
        (__attribute__((address_space(1))) void*)sp2,
        (__attribute__((address_space(3))) void*)(&Bt[b][(wid*4 + 2) * 512]), 16, 0, 0);
    __builtin_amdgcn_global_load_lds(
        (__attribute__((address_space(1))) void*)sp3,
        (__attribute__((address_space(3))) void*)(&Bt[b][(wid*4 + 3) * 512]), 16, 0, 0);
    sp0 += 64 * ND; sp1 += 64 * ND; sp2 += 64 * ND; sp3 += 64 * ND;
  };

  auto compute = [&](int s, int b){
    const int CT0 = C0 + s * 64;
    f32x4 acc[2][4];
    #pragma unroll
    for (int mt = 0; mt < 2; ++mt)
      #pragma unroll
      for (int nt = 0; nt < 4; ++nt){
        f32x4 z = {0.f, 0.f, 0.f, 0.f};
        acc[mt][nt] = z;
      }

    #pragma unroll
    for (int ks = 0; ks < 4; ++ks){
      const int t = ks * 4 + quad;                 // 16B chunk index in col
      // per-lane base; nt and buffer terms are compile-time -> fold into
      // the ds_read 16-bit offset immediate
      const u16* bb = &Bt[b][0] + m16 * 128 + ((t ^ m16) * 8);
      #pragma unroll
      for (int nt = 0; nt < 4; ++nt){
        const bf16x8 bfrag = *reinterpret_cast<const bf16x8*>(bb + nt * 2048);
        acc[0][nt] = __builtin_amdgcn_mfma_f32_16x16x32_bf16(afrag[0][ks], bfrag, acc[0][nt], 0, 0, 0);
        acc[1][nt] = __builtin_amdgcn_mfma_f32_16x16x32_bf16(afrag[1][ks], bfrag, acc[1][nt], 0, 0, 0);
      }
    }

    // epilogue: u = (sq_i + sq_j - 2g) * p_j  (no interior clamp; fin clamps)
    // colp loaded via the incremental pointer (nt*16 folds into the load
    // offset immediate); transient, not held across the MFMA block.
    #pragma unroll
    for (int nt = 0; nt < 4; ++nt){
      const float4 cp = cpp[nt * 16];
      const float pj   = cp.y;
      const float spj  = cp.z;
      const int   labj = __float_as_int(cp.w);
      const float n2pj = -2.0f * pj;
      #pragma unroll
      for (int mt = 0; mt < 2; ++mt){
        const bool tilediag = (WR0 + mt*16) == (CT0 + nt*16);
        if (!tilediag){
          #pragma unroll
          for (int r = 0; r < 4; ++r){
            const int idx = mt*4 + r;
            const float u = fmaf(n2pj, acc[mt][nt][r], fmaf(sqi[idx], pj, spj));
            const bool sm = (labi[idx] == labj);
            vpos[idx] = fmaxf(vpos[idx], sm ? u : NEGINF);
            vneg[idx] = fminf(vneg[idx], sm ? POSINF : u);
          }
        } else {
          #pragma unroll
          for (int r = 0; r < 4; ++r){
            const int idx = mt*4 + r;
            const float u = fmaf(n2pj, acc[mt][nt][r], fmaf(sqi[idx], pj, spj));
            const bool sm = (labi[idx] == labj);
            const bool dg = (m16 == quad*4 + r);
            vpos[idx] = fmaxf(vpos[idx], (sm && !dg) ? u : NEGINF);
            vneg[idx] = fminf(vneg[idx], sm ? POSINF : u);
          }
        }
      }
    }
    cpp += 64;                            // next half-tile's column params
  };

  // pipelined main loop, ROLLED: each iteration handles half-tiles
  // {2ss, 2ss+1} in buffers {0, 1}. Buffer indices are literals; stage/colp
  // addresses advance incrementally (stage order s=0..7, compute s=0..7).
  stage(0);                              // s=0 -> buf0
  __syncthreads();                       // drains vmcnt(0): tile 0 ready
  #pragma unroll 1
  for (int ss = 0; ss < 4; ++ss){
    const int s0 = ss * 2;
    stage(1);                            // s0+1 -> buf1 (buf1 consumed by
                                         // barrier at end of prev iter)
    compute(s0, 0);
    __syncthreads();                     // buf1 staged; buf0 consumed
    if (ss < 3) stage(0);                // s0+2 -> buf0
    compute(s0 + 1, 1);
    if (ss < 3) __syncthreads();         // buf0 staged; buf1 consumed
  }

  // row i lives in the 16 lanes of one quad-group: reduce across them
  #pragma unroll
  for (int i = 0; i < 8; ++i){
    #pragma unroll
    for (int m = 1; m < 16; m <<= 1){
      vpos[i] = fmaxf(vpos[i], __shfl_xor(vpos[i], m, 16));
      vneg[i] = fminf(vneg[i], __shfl_xor(vneg[i], m, 16));
    }
  }
  if (m16 == 0){
    #pragma unroll
    for (int i = 0; i < 8; ++i){
      const int row = WR0 + (i >> 2)*16 + quad*4 + (i & 3);
      ppos[blockIdx.y * NB + row] = vpos[i];
      pneg[blockIdx.y * NB + row] = vneg[i];
    }
  }
}

// ---- finalize (fused): 64 blocks x 128 rows -> atomic finish ---------------
extern "C" __global__ __launch_bounds__(128)
void fin_k(const float* __restrict__ ppos, const float* __restrict__ pneg,
           const float4* __restrict__ colp, float* __restrict__ gred,
           unsigned int* __restrict__ done, float* __restrict__ out)
{
  const int row = blockIdx.x * 128 + threadIdx.x;
  float up = NEGINF, un = POSINF;
  #pragma unroll
  for (int c = 0; c < NCHUNK; ++c){
    up = fmaxf(up, ppos[c * NB + row]);
    un = fminf(un, pneg[c * NB + row]);
  }
  const bool hp = (up > NEGINF);
  const bool hn = (un < POSINF);
  const float pi = colp[row].y;
  float dp = 0.0f, dn = 0.0f;
  // arccosh(1+t) = log1p(t + sqrt(t*(t+2))), t clamped at 1e-7 (matches ref)
  if (hp){ float t = fmaxf(2.0f * up * pi, 1e-7f); dp = log1pf(t + sqrtf(t * (t + 2.0f))); }
  if (hn){ float t = fmaxf(2.0f * un * pi, 1e-7f); dn = log1pf(t + sqrtf(t * (t + 2.0f))); }
  float lsum = (hp && hn) ? fmaxf(dp - dn + 0.5f, 0.0f) : 0.0f;
  float lcnt = (hp && hn) ? 1.0f : 0.0f;
  #pragma unroll
  for (int m = 1; m < 64; m <<= 1){
    lsum += __shfl_xor(lsum, m, 64);
    lcnt += __shfl_xor(lcnt, m, 64);
  }
  __shared__ float2 s_p[2];
  if ((threadIdx.x & 63) == 0) s_p[threadIdx.x >> 6] = make_float2(lsum, lcnt);
  __syncthreads();
  if (threadIdx.x == 0){
    const float bs = s_p[0].x + s_p[1].x;
    const float bc = s_p[0].y + s_p[1].y;
    atomicAdd(&gred[0], bs);
    atomicAdd(&gred[1], bc);
    __threadfence();
    const unsigned int prev = atomicAdd(done, 1u);
    if (prev == 63u){                      // last block: all adds visible
      __threadfence();
      const float s = atomicAdd(&gred[0], 0.0f);   // read via atomic (L2)
      const float c = atomicAdd(&gred[1], 0.0f);
      out[0] = (c > 0.0f) ? (s / c) : 0.0f;
    }
  }
}

extern "C" void kernel_launch(void* const* d_in, const int* in_sizes, int n_in,
                              void* d_out, int out_size, void* d_ws, size_t ws_size,
                              hipStream_t stream)
{
  const float* x  = (const float*)d_in[0];
  const int* lab  = (const int*)d_in[1];
  char* ws = (char*)d_ws;
  u16*    xb   = (u16*)ws;                                        // 2 MB
  float4* colp = (float4*)(ws + (size_t)2*1024*1024);             // 128 KB
  float*  ppos = (float*)(ws + (size_t)2*1024*1024 + 128*1024);   // 512 KB
  float*  pneg = (float*)(ws + (size_t)2*1024*1024 + 128*1024 + 512*1024); // 512 KB
  float*  gred = (float*)(ws + (size_t)2*1024*1024 + 128*1024 + 1024*1024); // 8 B
  unsigned int* done = (unsigned int*)(ws + (size_t)2*1024*1024 + 128*1024
                                          + 1024*1024 + 64);      // 4 B

  hipLaunchKernelGGL(prep_k, dim3(1024), dim3(256), 0, stream, x, lab, xb, colp,
                     gred, done);
  hipLaunchKernelGGL(gram_k, dim3(64, NCHUNK), dim3(256), 0, stream,
                     xb, colp, ppos, pneg);
  hipLaunchKernelGGL(fin_k, dim3(64), dim3(128), 0, stream, ppos, pneg, colp,
                     gred, done, (float*)d_out);
}

// Round 7
// 102.446 us; speedup vs baseline: 1.0127x; 1.0127x over previous
//
#include <hip/hip_runtime.h>
#include <hip/hip_bf16.h>

typedef __attribute__((ext_vector_type(8))) __bf16 bf16x8;
typedef __attribute__((ext_vector_type(4))) float f32x4;
typedef unsigned short u16;

#define NB 8192
#define ND 128
#define NCHUNK 16
#define NEGINF (-__builtin_inff())
#define POSINF (__builtin_inff())

__device__ inline u16 f2b(float f){
  __hip_bfloat16 h = __float2bfloat16(f);
  return *reinterpret_cast<u16*>(&h);
}

// ---- prep: fp32 -> bf16, colp[row] = (sq, p=1/(1-sq), sq*p, lab_bits) ------
// also zeroes the final-reduction cells so fin_k's atomic finish is
// graph-replay-safe (stream order: prep -> gram -> fin every iteration).
extern "C" __global__ __launch_bounds__(256)
void prep_k(const float* __restrict__ x, const int* __restrict__ lab,
            u16* __restrict__ xb, float4* __restrict__ colp,
            float* __restrict__ gred, unsigned int* __restrict__ done)
{
  if (blockIdx.x == 0 && threadIdx.x == 0){
    gred[0] = 0.0f; gred[1] = 0.0f; *done = 0u;
  }
  const int tid = blockIdx.x * 256 + threadIdx.x;
  const int row = tid >> 5;           // 32 threads per row
  const int sub = tid & 31;
  const float4 v = reinterpret_cast<const float4*>(x)[row * 32 + sub];
  float s = v.x*v.x + v.y*v.y + v.z*v.z + v.w*v.w;
  #pragma unroll
  for (int m = 1; m < 32; m <<= 1) s += __shfl_xor(s, m, 32);
  ushort4 o;
  o.x = f2b(v.x); o.y = f2b(v.y); o.z = f2b(v.z); o.w = f2b(v.w);
  reinterpret_cast<ushort4*>(xb)[row * 32 + sub] = o;
  if (sub == 0){
    const float p = 1.0f / (1.0f - s);
    colp[row] = make_float4(s, p, s * p, __int_as_float(lab[row]));
  }
}

// ---- main: bf16 MFMA gram tiles + streaming row max/min --------------------
// grid (64, 16): x = 128-row tile, y = 512-col chunk. 4 waves, each 32 rows.
// K-loop: 8 half-tiles of 64 cols, double-buffered in 2x16KB LDS; stage for
// half-tile s+1 issued before compute(s) (T3-minimum 2-phase).
// PRESSURE DISCIPLINE (rounds 1-2): (256,4) capped regs at 128 -> 20-90 MB
// scratch. (256,3) + rolled pipeline loop: 84 VGPR, no spill.
// ROUND-5: colp panel in LDS = bank conflicts + slower. Reverted.
// ROUND-6: incremental stage/colp addressing (neutral on time; WRITE now
// exactly 1.0 MB semantic).
// ROUND-7: wid through readfirstlane. threadIdx.x>>6 is wave-uniform but
// LLVM divergence analysis can't prove it -> the per-(mt,nt) tilediag
// if/else was exec-masked DUAL-PATH (both epilogue bodies executed,
// ~2x epilogue VALU; measured VALUBusy 41% vs ~18% semantic). With an
// SGPR wid the branch is s_cbranch (one path) and addressing scalarizes.
extern "C" __global__ __launch_bounds__(256, 3)
void gram_k(const u16* __restrict__ xb, const float4* __restrict__ colp,
            float* __restrict__ ppos, float* __restrict__ pneg)
{
  __shared__ u16 Bt[2][64 * 128];   // 2 x 16 KB double buffer, 256B/col,
                                    // 16B chunks XOR-swizzled by col&15
  const int wid  = __builtin_amdgcn_readfirstlane(threadIdx.x >> 6);
  const int lane = threadIdx.x & 63;
  const int m16  = lane & 15;
  const int quad = lane >> 4;
  const int R0  = blockIdx.x * 128;
  const int C0  = blockIdx.y * 512;
  const int WR0 = R0 + wid * 32;     // wave-uniform (SGPR)

  // A fragments in registers: A[m=lane&15][k=quad*8+j]
  bf16x8 afrag[2][4];
  #pragma unroll
  for (int mt = 0; mt < 2; ++mt){
    const u16* arow = xb + (WR0 + mt*16 + m16) * ND;
    #pragma unroll
    for (int ks = 0; ks < 4; ++ks)
      afrag[mt][ks] = *reinterpret_cast<const bf16x8*>(arow + ks*32 + quad*8);
  }

  // per-row (C/D row = quad*4 + r) params
  float sqi[8]; int labi[8];
  #pragma unroll
  for (int mt = 0; mt < 2; ++mt)
    #pragma unroll
    for (int r = 0; r < 4; ++r){
      const float4 cp = colp[WR0 + mt*16 + quad*4 + r];
      sqi[mt*4+r]  = cp.x;
      labi[mt*4+r] = __float_as_int(cp.w);
    }

  float vpos[8], vneg[8];
  #pragma unroll
  for (int i = 0; i < 8; ++i){ vpos[i] = NEGINF; vneg[i] = POSINF; }

  // Per-thread staging base pointers, computed ONCE. For chunk c (0..3):
  // brow(c) = wid*16 + c*4 + quad; src(c) = m16 ^ ((c*4+quad)&15)
  // (wid*16 drops out of the &15). addr(s,c) = base_c + s*64*ND.
  // Advanced by +64*ND after each stage call (stage order s = 0..7).
  const u16* sp0 = xb + (C0 + wid*16 + 0*4 + quad) * ND + (m16 ^ ((0*4 + quad) & 15)) * 8;
  const u16* sp1 = xb + (C0 + wid*16 + 1*4 + quad) * ND + (m16 ^ ((1*4 + quad) & 15)) * 8;
  const u16* sp2 = xb + (C0 + wid*16 + 2*4 + quad) * ND + (m16 ^ ((2*4 + quad) & 15)) * 8;
  const u16* sp3 = xb + (C0 + wid*16 + 3*4 + quad) * ND + (m16 ^ ((3*4 + quad) & 15)) * 8;
  // epilogue column-param pointer: advanced by +64 per compute (s = 0..7)
  const float4* cpp = colp + C0 + m16;

  // stage 64 B-rows (16 KB) into buffer b; then advance the base pointers.
  // LDS[col][slot] holds global chunk (slot ^ (col&15)); dest lane-linear.
  auto stage = [&](int b){
    __builtin_amdgcn_global_load_lds(
        (__attribute__((address_space(1))) void*)sp0,
        (__attribute__((address_space(3))) void*)(&Bt[b][(wid*4 + 0) * 512]), 16, 0, 0);
    __builtin_amdgcn_global_load_lds(
        (__attribute__((address_space(1))) void*)sp1,
        (__attribute__((address_space(3))) void*)(&Bt[b][(wid*4 + 1) * 512]), 16, 0, 0);
    __builtin_amdgcn_global_load_lds(
        (__attribute__((address_space(1))) void*)sp2,
        (__attribute__((address_space(3))) void*)(&Bt[b][(wid*4 + 2) * 512]), 16, 0, 0);
    __builtin_amdgcn_global_load_lds(
        (__attribute__((address_space(1))) void*)sp3,
        (__attribute__((address_space(3))) void*)(&Bt[b][(wid*4 + 3) * 512]), 16, 0, 0);
    sp0 += 64 * ND; sp1 += 64 * ND; sp2 += 64 * ND; sp3 += 64 * ND;
  };

  auto compute = [&](int s, int b){
    const int CT0 = C0 + s * 64;
    f32x4 acc[2][4];
    #pragma unroll
    for (int mt = 0; mt < 2; ++mt)
      #pragma unroll
      for (int nt = 0; nt < 4; ++nt){
        f32x4 z = {0.f, 0.f, 0.f, 0.f};
        acc[mt][nt] = z;
      }

    #pragma unroll
    for (int ks = 0; ks < 4; ++ks){
      const int t = ks * 4 + quad;                 // 16B chunk index in col
      // per-lane base; nt and buffer terms are compile-time -> fold into
      // the ds_read 16-bit offset immediate
      const u16* bb = &Bt[b][0] + m16 * 128 + ((t ^ m16) * 8);
      #pragma unroll
      for (int nt = 0; nt < 4; ++nt){
        const bf16x8 bfrag = *reinterpret_cast<const bf16x8*>(bb + nt * 2048);
        acc[0][nt] = __builtin_amdgcn_mfma_f32_16x16x32_bf16(afrag[0][ks], bfrag, acc[0][nt], 0, 0, 0);
        acc[1][nt] = __builtin_amdgcn_mfma_f32_16x16x32_bf16(afrag[1][ks], bfrag, acc[1][nt], 0, 0, 0);
      }
    }

    // epilogue: u = (sq_i + sq_j - 2g) * p_j  (no interior clamp; fin clamps)
    // colp loaded via the incremental pointer; transient. tilediag is
    // SGPR-uniform (wid via readfirstlane) -> s_cbranch, single path.
    #pragma unroll
    for (int nt = 0; nt < 4; ++nt){
      const float4 cp = cpp[nt * 16];
      const float pj   = cp.y;
      const float spj  = cp.z;
      const int   labj = __float_as_int(cp.w);
      const float n2pj = -2.0f * pj;
      #pragma unroll
      for (int mt = 0; mt < 2; ++mt){
        const bool tilediag = (WR0 + mt*16) == (CT0 + nt*16);
        if (!tilediag){
          #pragma unroll
          for (int r = 0; r < 4; ++r){
            const int idx = mt*4 + r;
            const float u = fmaf(n2pj, acc[mt][nt][r], fmaf(sqi[idx], pj, spj));
            const bool sm = (labi[idx] == labj);
            vpos[idx] = fmaxf(vpos[idx], sm ? u : NEGINF);
            vneg[idx] = fminf(vneg[idx], sm ? POSINF : u);
          }
        } else {
          #pragma unroll
          for (int r = 0; r < 4; ++r){
            const int idx = mt*4 + r;
            const float u = fmaf(n2pj, acc[mt][nt][r], fmaf(sqi[idx], pj, spj));
            const bool sm = (labi[idx] == labj);
            const bool dg = (m16 == quad*4 + r);
            vpos[idx] = fmaxf(vpos[idx], (sm && !dg) ? u : NEGINF);
            vneg[idx] = fminf(vneg[idx], sm ? POSINF : u);
          }
        }
      }
    }
    cpp += 64;                            // next half-tile's column params
  };

  // pipelined main loop, ROLLED: each iteration handles half-tiles
  // {2ss, 2ss+1} in buffers {0, 1}. Buffer indices are literals; stage/colp
  // addresses advance incrementally (stage order s=0..7, compute s=0..7).
  stage(0);                              // s=0 -> buf0
  __syncthreads();                       // drains vmcnt(0): tile 0 ready
  #pragma unroll 1
  for (int ss = 0; ss < 4; ++ss){
    const int s0 = ss * 2;
    stage(1);                            // s0+1 -> buf1 (buf1 consumed by
                                         // barrier at end of prev iter)
    compute(s0, 0);
    __syncthreads();                     // buf1 staged; buf0 consumed
    if (ss < 3) stage(0);                // s0+2 -> buf0
    compute(s0 + 1, 1);
    if (ss < 3) __syncthreads();         // buf0 staged; buf1 consumed
  }

  // row i lives in the 16 lanes of one quad-group: reduce across them
  #pragma unroll
  for (int i = 0; i < 8; ++i){
    #pragma unroll
    for (int m = 1; m < 16; m <<= 1){
      vpos[i] = fmaxf(vpos[i], __shfl_xor(vpos[i], m, 16));
      vneg[i] = fminf(vneg[i], __shfl_xor(vneg[i], m, 16));
    }
  }
  if (m16 == 0){
    #pragma unroll
    for (int i = 0; i < 8; ++i){
      const int row = WR0 + (i >> 2)*16 + quad*4 + (i & 3);
      ppos[blockIdx.y * NB + row] = vpos[i];
      pneg[blockIdx.y * NB + row] = vneg[i];
    }
  }
}

// ---- finalize (fused): 64 blocks x 128 rows -> atomic finish ---------------
extern "C" __global__ __launch_bounds__(128)
void fin_k(const float* __restrict__ ppos, const float* __restrict__ pneg,
           const float4* __restrict__ colp, float* __restrict__ gred,
           unsigned int* __restrict__ done, float* __restrict__ out)
{
  const int row = blockIdx.x * 128 + threadIdx.x;
  float up = NEGINF, un = POSINF;
  #pragma unroll
  for (int c = 0; c < NCHUNK; ++c){
    up = fmaxf(up, ppos[c * NB + row]);
    un = fminf(un, pneg[c * NB + row]);
  }
  const bool hp = (up > NEGINF);
  const bool hn = (un < POSINF);
  const float pi = colp[row].y;
  float dp = 0.0f, dn = 0.0f;
  // arccosh(1+t) = log1p(t + sqrt(t*(t+2))), t clamped at 1e-7 (matches ref)
  if (hp){ float t = fmaxf(2.0f * up * pi, 1e-7f); dp = log1pf(t + sqrtf(t * (t + 2.0f))); }
  if (hn){ float t = fmaxf(2.0f * un * pi, 1e-7f); dn = log1pf(t + sqrtf(t * (t + 2.0f))); }
  float lsum = (hp && hn) ? fmaxf(dp - dn + 0.5f, 0.0f) : 0.0f;
  float lcnt = (hp && hn) ? 1.0f : 0.0f;
  #pragma unroll
  for (int m = 1; m < 64; m <<= 1){
    lsum += __shfl_xor(lsum, m, 64);
    lcnt += __shfl_xor(lcnt, m, 64);
  }
  __shared__ float2 s_p[2];
  if ((threadIdx.x & 63) == 0) s_p[threadIdx.x >> 6] = make_float2(lsum, lcnt);
  __syncthreads();
  if (threadIdx.x == 0){
    const float bs = s_p[0].x + s_p[1].x;
    const float bc = s_p[0].y + s_p[1].y;
    atomicAdd(&gred[0], bs);
    atomicAdd(&gred[1], bc);
    __threadfence();
    const unsigned int prev = atomicAdd(done, 1u);
    if (prev == 63u){                      // last block: all adds visible
      __threadfence();
      const float s = atomicAdd(&gred[0], 0.0f);   // read via atomic (L2)
      const float c = atomicAdd(&gred[1], 0.0f);
      out[0] = (c > 0.0f) ? (s / c) : 0.0f;
    }
  }
}

extern "C" void kernel_launch(void* const* d_in, const int* in_sizes, int n_in,
                              void* d_out, int out_size, void* d_ws, size_t ws_size,
                              hipStream_t stream)
{
  const float* x  = (const float*)d_in[0];
  const int* lab  = (const int*)d_in[1];
  char* ws = (char*)d_ws;
  u16*    xb   = (u16*)ws;                                        // 2 MB
  float4* colp = (float4*)(ws + (size_t)2*1024*1024);             // 128 KB
  float*  ppos = (float*)(ws + (size_t)2*1024*1024 + 128*1024);   // 512 KB
  float*  pneg = (float*)(ws + (size_t)2*1024*1024 + 128*1024 + 512*1024); // 512 KB
  float*  gred = (float*)(ws + (size_t)2*1024*1024 + 128*1024 + 1024*1024); // 8 B
  unsigned int* done = (unsigned int*)(ws + (size_t)2*1024*1024 + 128*1024
                                          + 1024*1024 + 64);      // 4 B

  hipLaunchKernelGGL(prep_k, dim3(1024), dim3(256), 0, stream, x, lab, xb, colp,
                     gred, done);
  hipLaunchKernelGGL(gram_k, dim3(64, NCHUNK), dim3(256), 0, stream,
                     xb, colp, ppos, pneg);
  hipLaunchKernelGGL(fin_k, dim3(64), dim3(128), 0, stream, ppos, pneg, colp,
                     gred, done, (float*)d_out);
}